// Round 1
// baseline (695.990 us; speedup 1.0000x reference)
//
#include <hip/hip_runtime.h>
#include <math.h>

#define BB 4
#define HH 16
#define SS 8192
#define HDD 64
#define DD 1024
#define MEM 65536
#define KT 10

// ---------------- output offsets (floats) ----------------
// o0 inputs      33554432
// o1 q           33554432
// o2 aug_k       33595392   (B,H,S+KT,HD)
// o3 aug_v       33595392
// o4 aug_mask    32808
// o5 aug_pos     32808
// o6 new_events  33554432
// o7 event_len   32768
static const long O0 = 0;
static const long O1 = 33554432;
static const long O2 = 67108864;
static const long O3 = 100704256;
static const long O4 = 134299648;
static const long O5 = 134332456;
static const long O6 = 134365264;
static const long O7 = 167919696;

// ---------------- ws layout (bytes) ----------------
// 0        double surprise[B*S]   262144
// 262144   float  sims[B*MEM]     1048576   -> 1310720
// 1310720  int    bpos[B*S]       131072    -> 1441792
// 1441792  int    nseg[B]
// 1441824  int    idx[B*KT]
// 1442048  double qn[B]

// ------------------------------------------------------------------
__global__ void copy_f4_kernel(const float4* __restrict__ src,
                               float4* __restrict__ dst, long n4) {
    long i = (long)blockIdx.x * blockDim.x + threadIdx.x;
    long stride = (long)gridDim.x * blockDim.x;
    for (; i < n4; i += stride) dst[i] = src[i];
}

// copy k (B,H,S,HD) into aug interior rows [KT, KT+S) of (B,H,S+KT,HD)
__global__ void interior_copy_kernel(const float4* __restrict__ src,
                                     float4* __restrict__ dst) {
    const long n4 = (long)BB * HH * SS * HDD / 4;  // 8388608
    long i = (long)blockIdx.x * blockDim.x + threadIdx.x;
    long stride = (long)gridDim.x * blockDim.x;
    for (; i < n4; i += stride) {
        long chunk = i >> 17;          // S*HD/4 = 131072
        long r = i & 131071;
        dst[chunk * 131232 + 160 + r] = src[i];  // (S+KT)*HD/4 = 131232, KT*HD/4=160
    }
}

// surprise[b,s] = || kf[b,s]-kf[b,s-1] ||  (fp64), one wave per (b,s)
__global__ __launch_bounds__(256) void surprise_kernel(
        const float* __restrict__ k, double* __restrict__ surprise) {
    int wid = (int)(((long)blockIdx.x * blockDim.x + threadIdx.x) >> 6);
    int lane = threadIdx.x & 63;
    if (wid >= BB * SS) return;
    int b = wid >> 13;
    int s = wid & (SS - 1);
    double acc = 0.0;
    if (s > 0) {
        const float* kb = k + (long)b * HH * SS * HDD;
        for (int h = 0; h < HH; ++h) {
            long off = ((long)h * SS + s) * HDD + lane;
            double d = (double)kb[off] - (double)kb[off - HDD];
            acc += d * d;
        }
        for (int m = 32; m >= 1; m >>= 1) acc += __shfl_xor(acc, m, 64);
    }
    if (lane == 0) surprise[wid] = (s == 0) ? 0.0 : sqrt(acc);
}

// per-batch: mean/std(ddof=1) -> threshold -> boundary mask -> scan -> bpos
__global__ __launch_bounds__(1024) void stats_scan_kernel(
        const double* __restrict__ surprise, int* __restrict__ bpos,
        int* __restrict__ nseg) {
    int b = blockIdx.x;
    int tid = threadIdx.x;
    const double* sp = surprise + (long)b * SS;
    double loc[8];
    double sum = 0.0;
    for (int j = 0; j < 8; ++j) { loc[j] = sp[tid * 8 + j]; sum += loc[j]; }
    __shared__ double sd[1024];
    sd[tid] = sum;
    __syncthreads();
    for (int off = 512; off >= 1; off >>= 1) {
        if (tid < off) sd[tid] += sd[tid + off];
        __syncthreads();
    }
    double mean = sd[0] / SS;
    __syncthreads();
    double vs = 0.0;
    for (int j = 0; j < 8; ++j) { double d = loc[j] - mean; vs += d * d; }
    sd[tid] = vs;
    __syncthreads();
    for (int off = 512; off >= 1; off >>= 1) {
        if (tid < off) sd[tid] += sd[tid + off];
        __syncthreads();
    }
    double thr = mean + 0.5 * sqrt(sd[0] / (SS - 1));
    __syncthreads();

    int bi[8];
    int cnt = 0;
    for (int j = 0; j < 8; ++j) {
        int s = tid * 8 + j;
        bi[j] = (s == SS - 1) || (loc[j] > thr);
        cnt += bi[j];
    }
    __shared__ int si[1024];
    si[tid] = cnt;
    __syncthreads();
    for (int off = 1; off < 1024; off <<= 1) {
        int v = 0;
        if (tid >= off) v = si[tid - off];
        __syncthreads();
        si[tid] += v;
        __syncthreads();
    }
    int run = si[tid] - cnt;  // exclusive prefix
    for (int j = 0; j < 8; ++j) {
        if (bi[j]) { bpos[(long)b * SS + run] = tid * 8 + j; ++run; }
    }
    if (tid == 1023) nseg[b] = si[1023];
}

// qn[b] = max(||kf[b,S-1]||, EPS)
__global__ __launch_bounds__(1024) void qnorm_kernel(
        const float* __restrict__ k, double* __restrict__ qn) {
    int b = blockIdx.x;
    int tid = threadIdx.x;
    float v = k[(((long)b * HH + (tid >> 6)) * SS + (SS - 1)) * HDD + (tid & 63)];
    __shared__ double sd[1024];
    sd[tid] = (double)v * (double)v;
    __syncthreads();
    for (int off = 512; off >= 1; off >>= 1) {
        if (tid < off) sd[tid] += sd[tid + off];
        __syncthreads();
    }
    if (tid == 0) qn[b] = fmax(sqrt(sd[0]), 1e-8);
}

// sims[b,e] = dot(query_b, events_e) / (qn_b * max(||events_e||,EPS))
__global__ __launch_bounds__(256) void sims_kernel(
        const float* __restrict__ events, const float* __restrict__ k,
        const double* __restrict__ qn, float* __restrict__ sims) {
    __shared__ float ql[BB][DD];
    __shared__ double qns[BB];
    int tid = threadIdx.x;
    for (int j = tid; j < BB * DD; j += 256) {
        int b = j >> 10;
        int e = j & 1023;
        ql[b][e] = k[(((long)b * HH + (e >> 6)) * SS + (SS - 1)) * HDD + (e & 63)];
    }
    if (tid < BB) qns[tid] = qn[tid];
    __syncthreads();
    int w = tid >> 6;
    int lane = tid & 63;
    long e = (long)blockIdx.x * 4 + w;  // one event row per wave
    const float* er = events + e * DD;
    double en = 0.0, d0 = 0.0, d1 = 0.0, d2 = 0.0, d3 = 0.0;
    for (int it = 0; it < DD / 64; ++it) {
        int j = lane + it * 64;
        double v = (double)er[j];
        en += v * v;
        d0 += v * (double)ql[0][j];
        d1 += v * (double)ql[1][j];
        d2 += v * (double)ql[2][j];
        d3 += v * (double)ql[3][j];
    }
    for (int m = 32; m >= 1; m >>= 1) {
        en += __shfl_xor(en, m, 64);
        d0 += __shfl_xor(d0, m, 64);
        d1 += __shfl_xor(d1, m, 64);
        d2 += __shfl_xor(d2, m, 64);
        d3 += __shfl_xor(d3, m, 64);
    }
    if (lane == 0) {
        double enn = fmax(sqrt(en), 1e-8);
        sims[0 * (long)MEM + e] = (float)(d0 / (qns[0] * enn));
        sims[1 * (long)MEM + e] = (float)(d1 / (qns[1] * enn));
        sims[2 * (long)MEM + e] = (float)(d2 / (qns[2] * enn));
        sims[3 * (long)MEM + e] = (float)(d3 / (qns[3] * enn));
    }
}

// top-10 per batch, ties -> lowest index (matches jax.lax.top_k)
__global__ __launch_bounds__(1024) void topk_kernel(
        const float* __restrict__ sims, int* __restrict__ idxout) {
    int b = blockIdx.x;
    int tid = threadIdx.x;
    const float* sb = sims + (long)b * MEM;
    __shared__ float bv[1024];
    __shared__ int bix[1024];
    __shared__ int chosen[KT];
    for (int p = 0; p < KT; ++p) {
        float best = -INFINITY;
        int bi_ = 0x7fffffff;
        for (int it = 0; it < MEM / 1024; ++it) {
            int e = tid + it * 1024;  // increasing order per thread
            bool skip = false;
            for (int c = 0; c < p; ++c)
                if (chosen[c] == e) skip = true;
            if (skip) continue;
            float v = sb[e];
            if (v > best) { best = v; bi_ = e; }
        }
        bv[tid] = best;
        bix[tid] = bi_;
        __syncthreads();
        for (int off = 512; off >= 1; off >>= 1) {
            if (tid < off) {
                if (bv[tid + off] > bv[tid] ||
                    (bv[tid + off] == bv[tid] && bix[tid + off] < bix[tid])) {
                    bv[tid] = bv[tid + off];
                    bix[tid] = bix[tid + off];
                }
            }
            __syncthreads();
        }
        if (tid == 0) {
            chosen[p] = bix[0];
            idxout[b * KT + p] = bix[0];
        }
        __syncthreads();
    }
}

// scatter top-k event rows into the fronts of aug_k / aug_v
__global__ __launch_bounds__(1024) void gather_kernel(
        const float* __restrict__ events, const int* __restrict__ idxin,
        float* __restrict__ aug_k, float* __restrict__ aug_v) {
    int blk = blockIdx.x;  // B*KT = 40
    int b = blk / KT;
    int t = blk % KT;
    int tid = threadIdx.x;  // == D
    int ev = idxin[b * KT + t];
    float v = events[(long)ev * DD + tid];
    int h = tid >> 6;
    int d = tid & 63;
    long dst = (((long)b * HH + h) * (SS + KT) + t) * HDD + d;
    aug_k[dst] = v;
    aug_v[dst] = v;
}

// segment means -> new_events, counts -> event_lengths (zeros past nseg)
__global__ __launch_bounds__(256) void segmean_kernel(
        const float* __restrict__ k, const int* __restrict__ bpos,
        const int* __restrict__ nseg, float* __restrict__ new_events,
        float* __restrict__ event_lengths) {
    int j = blockIdx.x;  // segment slot in [0,S)
    int b = blockIdx.y;
    int tid = threadIdx.x;
    float* row = new_events + ((long)b * SS + j) * DD;
    int ns = nseg[b];
    if (j >= ns) {
        for (int c = 0; c < 4; ++c) row[tid + 256 * c] = 0.0f;
        if (tid == 0) event_lengths[(long)b * SS + j] = 0.0f;
        return;
    }
    int start = (j == 0) ? 0 : bpos[(long)b * SS + j - 1] + 1;
    int end = bpos[(long)b * SS + j];
    int len = end - start + 1;
    double acc0 = 0.0, acc1 = 0.0, acc2 = 0.0, acc3 = 0.0;
    for (int s = start; s <= end; ++s) {
        int dd0 = tid;
        acc0 += (double)k[(((long)b * HH + (dd0 >> 6)) * SS + s) * HDD + (dd0 & 63)];
        int dd1 = tid + 256;
        acc1 += (double)k[(((long)b * HH + (dd1 >> 6)) * SS + s) * HDD + (dd1 & 63)];
        int dd2 = tid + 512;
        acc2 += (double)k[(((long)b * HH + (dd2 >> 6)) * SS + s) * HDD + (dd2 & 63)];
        int dd3 = tid + 768;
        acc3 += (double)k[(((long)b * HH + (dd3 >> 6)) * SS + s) * HDD + (dd3 & 63)];
    }
    double inv = 1.0 / (double)len;
    row[tid] = (float)(acc0 * inv);
    row[tid + 256] = (float)(acc1 * inv);
    row[tid + 512] = (float)(acc2 * inv);
    row[tid + 768] = (float)(acc3 * inv);
    if (tid == 0) event_lengths[(long)b * SS + j] = (float)len;
}

// aug_mask and aug_positions
__global__ void maskpos_kernel(const float* __restrict__ amask,
                               const void* __restrict__ seqp,
                               float* __restrict__ out_mask,
                               float* __restrict__ out_pos) {
    int iv = ((const int*)seqp)[0];
    int seqlen;
    if (iv > 0 && iv < (1 << 24)) seqlen = iv;
    else seqlen = (int)(((const float*)seqp)[0]);
    int cp = seqlen - 1;
    int n = BB * (SS + KT);
    int i = blockIdx.x * blockDim.x + threadIdx.x;
    int stride = gridDim.x * blockDim.x;
    for (; i < n; i += stride) {
        int b = i / (SS + KT);
        int t = i - b * (SS + KT);
        out_mask[i] = (t < KT) ? 1.0f : amask[(long)b * SS + t - KT];
        out_pos[i] = (t < KT) ? (float)(cp - KT + t) : (float)(t - KT);
    }
}

extern "C" void kernel_launch(void* const* d_in, const int* in_sizes, int n_in,
                              void* d_out, int out_size, void* d_ws, size_t ws_size,
                              hipStream_t stream) {
    const float* in_inputs = (const float*)d_in[0];
    const float* in_q = (const float*)d_in[1];
    const float* in_k = (const float*)d_in[2];
    const float* in_v = (const float*)d_in[3];
    const float* in_amask = (const float*)d_in[4];
    const float* in_events = (const float*)d_in[5];
    const void* in_seq = d_in[6];
    float* out = (float*)d_out;

    char* ws = (char*)d_ws;
    double* surprise = (double*)ws;
    float* sims = (float*)(ws + 262144);
    int* bpos = (int*)(ws + 1310720);
    int* nseg = (int*)(ws + 1441792);
    int* idxw = (int*)(ws + 1441824);
    double* qn = (double*)(ws + 1442048);

    const long n4_big = 33554432L / 4;

    copy_f4_kernel<<<2048, 256, 0, stream>>>((const float4*)in_inputs,
                                             (float4*)(out + O0), n4_big);
    copy_f4_kernel<<<2048, 256, 0, stream>>>((const float4*)in_q,
                                             (float4*)(out + O1), n4_big);
    interior_copy_kernel<<<2048, 256, 0, stream>>>((const float4*)in_k,
                                                   (float4*)(out + O2));
    interior_copy_kernel<<<2048, 256, 0, stream>>>((const float4*)in_v,
                                                   (float4*)(out + O3));
    surprise_kernel<<<8192, 256, 0, stream>>>(in_k, surprise);
    stats_scan_kernel<<<4, 1024, 0, stream>>>(surprise, bpos, nseg);
    qnorm_kernel<<<4, 1024, 0, stream>>>(in_k, qn);
    sims_kernel<<<MEM / 4, 256, 0, stream>>>(in_events, in_k, qn, sims);
    topk_kernel<<<4, 1024, 0, stream>>>(sims, idxw);
    gather_kernel<<<BB * KT, 1024, 0, stream>>>(in_events, idxw, out + O2, out + O3);
    dim3 sg(SS, BB);
    segmean_kernel<<<sg, 256, 0, stream>>>(in_k, bpos, nseg, out + O6, out + O7);
    maskpos_kernel<<<64, 256, 0, stream>>>(in_amask, in_seq, out + O4, out + O5);
}

// Round 2
// 525.574 us; speedup vs baseline: 1.3242x; 1.3242x over previous
//
#include <hip/hip_runtime.h>
#include <math.h>

#define BB 4
#define HH 16
#define SS 8192
#define HDD 64
#define DD 1024
#define MEM 65536
#define KT 10

// ---------------- output offsets (floats) ----------------
static const long O0 = 0;          // inputs      33554432
static const long O1 = 33554432;   // q           33554432
static const long O2 = 67108864;   // aug_k       33595392 (B,H,S+KT,HD)
static const long O3 = 100704256;  // aug_v       33595392
static const long O4 = 134299648;  // aug_mask    32808
static const long O5 = 134332456;  // aug_pos     32808
static const long O6 = 134365264;  // new_events  33554432
static const long O7 = 167919696;  // event_len   32768

// ---------------- ws layout (bytes) ----------------
// 0        double surprise[B*S]        262144
// 262144   float  sims[B*MEM]          1048576  -> 1310720
// 1310720  int    bpos[B*S]            131072   -> 1441792
// 1441792  int    nseg[B]
// 1441824  int    idx[B*KT]
// 1442048  double qn[B]
// 1442304  float  cval[B*16*10]        2560
// 1444864  int    cidx[B*16*10]        2560     -> 1447424
// 1572864  double partial[B*H*S]       4194304  -> 5767168  (fused path only)
#define WS_NEED_FUSED 5767168UL

typedef float __attribute__((ext_vector_type(4))) f4v;

static __device__ __forceinline__ void nt_store4(float4* p, float4 v) {
    f4v t; t.x = v.x; t.y = v.y; t.z = v.z; t.w = v.w;
    __builtin_nontemporal_store(t, (f4v*)p);
}
static __device__ __forceinline__ float4 nt_load4(const float4* p) {
    f4v t = __builtin_nontemporal_load((const f4v*)p);
    float4 v; v.x = t.x; v.y = t.y; v.z = t.z; v.w = t.w;
    return v;
}

// ------------------------------------------------------------------
// One fused pass over all 4 big arrays (inputs, q, k, v).
// Region 2 (k) additionally computes per-(b,h,s) partial surprise sums.
#define N4REG 8388608L  // floats4 per 128MB region
__global__ __launch_bounds__(256) void bigmove_kernel(
        const float4* __restrict__ in0, const float4* __restrict__ q,
        const float4* __restrict__ k, const float4* __restrict__ v,
        float4* __restrict__ out4, double* __restrict__ partial,
        int do_part) {
    long i = (long)blockIdx.x * 256 + threadIdx.x;
    const long stride = (long)gridDim.x * 256;
    const long total = 4 * N4REG;
    for (; i < total; i += stride) {
        int region = (int)(i >> 23);
        long rel = i & (N4REG - 1);
        if (region == 0) {
            nt_store4(out4 + (O0 >> 2) + rel, nt_load4(in0 + rel));
        } else if (region == 1) {
            nt_store4(out4 + (O1 >> 2) + rel, nt_load4(q + rel));
        } else if (region == 3) {
            long chunk = rel >> 17;          // (b*H+h), 131072 float4 per slice
            long r = rel & 131071;
            nt_store4(out4 + (O3 >> 2) + chunk * 131232 + 160 + r,
                      nt_load4(v + rel));
        } else {  // region 2: k interior copy + surprise partials
            long chunk = rel >> 17;
            long r = rel & 131071;
            float4 cur = k[rel];  // normal load: keep k cached for segmean
            nt_store4(out4 + (O2 >> 2) + chunk * 131232 + 160 + r, cur);
            if (do_part) {
                int s = (int)(r >> 4);  // 16 float4 per row
                if (s > 0) {
                    float4 pv = k[rel - 16];
                    double dx = (double)cur.x - (double)pv.x;
                    double dy = (double)cur.y - (double)pv.y;
                    double dz = (double)cur.z - (double)pv.z;
                    double dw = (double)cur.w - (double)pv.w;
                    double acc = dx * dx + dy * dy + dz * dz + dw * dw;
                    // reduce over the 16-lane group that owns this row
                    acc += __shfl_xor(acc, 1, 64);
                    acc += __shfl_xor(acc, 2, 64);
                    acc += __shfl_xor(acc, 4, 64);
                    acc += __shfl_xor(acc, 8, 64);
                    if ((threadIdx.x & 15) == 0)
                        partial[chunk * SS + s] = acc;
                }
            }
        }
    }
}

// surprise[b,s] = sqrt( sum_h partial[(b*H+h)*S + s] ), 0 at s==0
__global__ __launch_bounds__(256) void surprise_reduce_kernel(
        const double* __restrict__ partial, double* __restrict__ surprise) {
    int t = blockIdx.x * 256 + threadIdx.x;
    if (t >= BB * SS) return;
    int b = t >> 13;
    int s = t & (SS - 1);
    double acc = 0.0;
    if (s > 0) {
        for (int h = 0; h < HH; ++h)
            acc += partial[(((long)(b * HH + h)) << 13) + s];
    }
    surprise[t] = (s == 0) ? 0.0 : sqrt(acc);
}

// fallback (small ws): standalone surprise pass reading k directly
__global__ __launch_bounds__(256) void surprise_fallback_kernel(
        const float* __restrict__ k, double* __restrict__ surprise) {
    int wid = (int)(((long)blockIdx.x * blockDim.x + threadIdx.x) >> 6);
    int lane = threadIdx.x & 63;
    if (wid >= BB * SS) return;
    int b = wid >> 13;
    int s = wid & (SS - 1);
    double acc = 0.0;
    if (s > 0) {
        const float* kb = k + (long)b * HH * SS * HDD;
        for (int h = 0; h < HH; ++h) {
            long off = ((long)h * SS + s) * HDD + lane;
            double d = (double)kb[off] - (double)kb[off - HDD];
            acc += d * d;
        }
        for (int m = 32; m >= 1; m >>= 1) acc += __shfl_xor(acc, m, 64);
    }
    if (lane == 0) surprise[wid] = (s == 0) ? 0.0 : sqrt(acc);
}

// per-batch: mean/std(ddof=1) -> threshold -> boundary mask -> scan -> bpos
__global__ __launch_bounds__(1024) void stats_scan_kernel(
        const double* __restrict__ surprise, int* __restrict__ bpos,
        int* __restrict__ nseg) {
    int b = blockIdx.x;
    int tid = threadIdx.x;
    const double* sp = surprise + (long)b * SS;
    double loc[8];
    double sum = 0.0;
    for (int j = 0; j < 8; ++j) { loc[j] = sp[tid * 8 + j]; sum += loc[j]; }
    __shared__ double sd[1024];
    sd[tid] = sum;
    __syncthreads();
    for (int off = 512; off >= 1; off >>= 1) {
        if (tid < off) sd[tid] += sd[tid + off];
        __syncthreads();
    }
    double mean = sd[0] / SS;
    __syncthreads();
    double vs = 0.0;
    for (int j = 0; j < 8; ++j) { double d = loc[j] - mean; vs += d * d; }
    sd[tid] = vs;
    __syncthreads();
    for (int off = 512; off >= 1; off >>= 1) {
        if (tid < off) sd[tid] += sd[tid + off];
        __syncthreads();
    }
    double thr = mean + 0.5 * sqrt(sd[0] / (SS - 1));
    __syncthreads();

    int bi[8];
    int cnt = 0;
    for (int j = 0; j < 8; ++j) {
        int s = tid * 8 + j;
        bi[j] = (s == SS - 1) || (loc[j] > thr);
        cnt += bi[j];
    }
    __shared__ int si[1024];
    si[tid] = cnt;
    __syncthreads();
    for (int off = 1; off < 1024; off <<= 1) {
        int v = 0;
        if (tid >= off) v = si[tid - off];
        __syncthreads();
        si[tid] += v;
        __syncthreads();
    }
    int run = si[tid] - cnt;  // exclusive prefix
    for (int j = 0; j < 8; ++j) {
        if (bi[j]) { bpos[(long)b * SS + run] = tid * 8 + j; ++run; }
    }
    if (tid == 1023) nseg[b] = si[1023];
}

// qn[b] = max(||kf[b,S-1]||, EPS)
__global__ __launch_bounds__(1024) void qnorm_kernel(
        const float* __restrict__ k, double* __restrict__ qn) {
    int b = blockIdx.x;
    int tid = threadIdx.x;
    float v = k[(((long)b * HH + (tid >> 6)) * SS + (SS - 1)) * HDD + (tid & 63)];
    __shared__ double sd[1024];
    sd[tid] = (double)v * (double)v;
    __syncthreads();
    for (int off = 512; off >= 1; off >>= 1) {
        if (tid < off) sd[tid] += sd[tid + off];
        __syncthreads();
    }
    if (tid == 0) qn[b] = fmax(sqrt(sd[0]), 1e-8);
}

// sims[b,e] = dot(query_b, events_e) / (qn_b * max(||events_e||,EPS))
// float4 event loads; query staged de-interleaved in LDS (conflict-free).
__global__ __launch_bounds__(256) void sims_kernel(
        const float4* __restrict__ events4, const float* __restrict__ k,
        const double* __restrict__ qn, float* __restrict__ sims) {
    __shared__ float qls[4][BB][256];  // [component c][batch][float4 idx]
    __shared__ double qns[BB];
    int tid = threadIdx.x;
    for (int j = tid; j < BB * DD; j += 256) {
        int b = j >> 10;
        int e = j & 1023;
        float val = k[(((long)b * HH + (e >> 6)) * SS + (SS - 1)) * HDD + (e & 63)];
        qls[e & 3][b][e >> 2] = val;
    }
    if (tid < BB) qns[tid] = qn[tid];
    __syncthreads();
    int w = tid >> 6;
    int lane = tid & 63;
    long e = (long)blockIdx.x * 4 + w;  // one event row per wave
    const float4* er = events4 + e * 256;
    double en = 0.0, d0 = 0.0, d1 = 0.0, d2 = 0.0, d3 = 0.0;
    for (int it = 0; it < 4; ++it) {
        int j4 = lane + it * 64;
        float4 ev = er[j4];
        double v0 = ev.x, v1 = ev.y, v2 = ev.z, v3 = ev.w;
        en += v0 * v0 + v1 * v1 + v2 * v2 + v3 * v3;
        d0 += v0 * (double)qls[0][0][j4] + v1 * (double)qls[1][0][j4] +
              v2 * (double)qls[2][0][j4] + v3 * (double)qls[3][0][j4];
        d1 += v0 * (double)qls[0][1][j4] + v1 * (double)qls[1][1][j4] +
              v2 * (double)qls[2][1][j4] + v3 * (double)qls[3][1][j4];
        d2 += v0 * (double)qls[0][2][j4] + v1 * (double)qls[1][2][j4] +
              v2 * (double)qls[2][2][j4] + v3 * (double)qls[3][2][j4];
        d3 += v0 * (double)qls[0][3][j4] + v1 * (double)qls[1][3][j4] +
              v2 * (double)qls[2][3][j4] + v3 * (double)qls[3][3][j4];
    }
    for (int m = 32; m >= 1; m >>= 1) {
        en += __shfl_xor(en, m, 64);
        d0 += __shfl_xor(d0, m, 64);
        d1 += __shfl_xor(d1, m, 64);
        d2 += __shfl_xor(d2, m, 64);
        d3 += __shfl_xor(d3, m, 64);
    }
    if (lane == 0) {
        double enn = fmax(sqrt(en), 1e-8);
        sims[0 * (long)MEM + e] = (float)(d0 / (qns[0] * enn));
        sims[1 * (long)MEM + e] = (float)(d1 / (qns[1] * enn));
        sims[2 * (long)MEM + e] = (float)(d2 / (qns[2] * enn));
        sims[3 * (long)MEM + e] = (float)(d3 / (qns[3] * enn));
    }
}

// stage 1: per (batch, partition of 4096) exact top-10, ties -> lowest index
__global__ __launch_bounds__(256) void topk_part_kernel(
        const float* __restrict__ sims, float* __restrict__ cval,
        int* __restrict__ cidx) {
    int blk = blockIdx.x;  // b*16 + part
    int b = blk >> 4;
    int part = blk & 15;
    const float* sb = sims + (long)b * MEM + part * 4096;
    int base = part * 4096;
    int tid = threadIdx.x;
    __shared__ float bv[256];
    __shared__ int bix[256];
    __shared__ int chosen[KT];
    for (int p = 0; p < KT; ++p) {
        float best = -INFINITY;
        int bi = 0x7fffffff;
        for (int it = 0; it < 16; ++it) {
            int e = tid + it * 256;  // increasing per thread
            bool skip = false;
            for (int c = 0; c < p; ++c)
                if (chosen[c] == e) skip = true;
            if (skip) continue;
            float v = sb[e];
            if (v > best) { best = v; bi = e; }
        }
        bv[tid] = best;
        bix[tid] = bi;
        __syncthreads();
        for (int off = 128; off >= 1; off >>= 1) {
            if (tid < off) {
                if (bv[tid + off] > bv[tid] ||
                    (bv[tid + off] == bv[tid] && bix[tid + off] < bix[tid])) {
                    bv[tid] = bv[tid + off];
                    bix[tid] = bix[tid + off];
                }
            }
            __syncthreads();
        }
        if (tid == 0) {
            chosen[p] = bix[0];
            cval[blk * KT + p] = bv[0];
            cidx[blk * KT + p] = base + bix[0];
        }
        __syncthreads();
    }
}

// stage 2: merge 16*10 candidates per batch -> global top-10
__global__ __launch_bounds__(256) void topk_merge_kernel(
        const float* __restrict__ cval, const int* __restrict__ cidx,
        int* __restrict__ idxout) {
    int b = blockIdx.x;
    int tid = threadIdx.x;
    __shared__ float v[256];
    __shared__ int ix[256];
    float mv = -INFINITY;
    int mi = 0x7fffffff;
    if (tid < 160) { mv = cval[b * 160 + tid]; mi = cidx[b * 160 + tid]; }
    v[tid] = mv;
    ix[tid] = mi;
    __syncthreads();
    if (tid == 0) {
        for (int p = 0; p < KT; ++p) {
            float best = -INFINITY;
            int bi = 0x7fffffff;
            int bslot = 0;
            for (int j = 0; j < 160; ++j) {
                if (v[j] > best || (v[j] == best && ix[j] < bi)) {
                    best = v[j];
                    bi = ix[j];
                    bslot = j;
                }
            }
            idxout[b * KT + p] = bi;
            v[bslot] = -INFINITY;
            ix[bslot] = 0x7fffffff;
        }
    }
}

// scatter top-k event rows into the fronts of aug_k / aug_v
__global__ __launch_bounds__(1024) void gather_kernel(
        const float* __restrict__ events, const int* __restrict__ idxin,
        float* __restrict__ aug_k, float* __restrict__ aug_v) {
    int blk = blockIdx.x;  // B*KT = 40
    int b = blk / KT;
    int t = blk % KT;
    int tid = threadIdx.x;  // == D
    int ev = idxin[b * KT + t];
    float v = events[(long)ev * DD + tid];
    int h = tid >> 6;
    int d = tid & 63;
    long dst = (((long)b * HH + h) * (SS + KT) + t) * HDD + d;
    aug_k[dst] = v;
    aug_v[dst] = v;
}

// segment means -> new_events (float4 path), counts -> event_lengths
__global__ __launch_bounds__(256) void segmean_kernel(
        const float4* __restrict__ k4, const int* __restrict__ bpos,
        const int* __restrict__ nseg, float4* __restrict__ ne4,
        float* __restrict__ event_lengths) {
    int j = blockIdx.x;  // segment slot in [0,S)
    int b = blockIdx.y;
    int tid = threadIdx.x;
    float4* row = ne4 + ((long)b * SS + j) * 256;
    int ns = nseg[b];
    if (j >= ns) {
        nt_store4(row + tid, make_float4(0.f, 0.f, 0.f, 0.f));
        if (tid == 0) event_lengths[(long)b * SS + j] = 0.0f;
        return;
    }
    int start = (j == 0) ? 0 : bpos[(long)b * SS + j - 1] + 1;
    int end = bpos[(long)b * SS + j];
    const float4* kb = k4 + ((long)(b * HH + (tid >> 4)) * SS) * 16 + (tid & 15);
    double a0 = 0.0, a1 = 0.0, a2 = 0.0, a3 = 0.0;
    for (int s = start; s <= end; ++s) {
        float4 x = kb[(long)s * 16];
        a0 += (double)x.x;
        a1 += (double)x.y;
        a2 += (double)x.z;
        a3 += (double)x.w;
    }
    double inv = 1.0 / (double)(end - start + 1);
    nt_store4(row + tid, make_float4((float)(a0 * inv), (float)(a1 * inv),
                                     (float)(a2 * inv), (float)(a3 * inv)));
    if (tid == 0) event_lengths[(long)b * SS + j] = (float)(end - start + 1);
}

// aug_mask and aug_positions
__global__ void maskpos_kernel(const float* __restrict__ amask,
                               const void* __restrict__ seqp,
                               float* __restrict__ out_mask,
                               float* __restrict__ out_pos) {
    int iv = ((const int*)seqp)[0];
    int seqlen;
    if (iv > 0 && iv < (1 << 24)) seqlen = iv;
    else seqlen = (int)(((const float*)seqp)[0]);
    int cp = seqlen - 1;
    int n = BB * (SS + KT);
    int i = blockIdx.x * blockDim.x + threadIdx.x;
    int stride = gridDim.x * blockDim.x;
    for (; i < n; i += stride) {
        int b = i / (SS + KT);
        int t = i - b * (SS + KT);
        out_mask[i] = (t < KT) ? 1.0f : amask[(long)b * SS + t - KT];
        out_pos[i] = (t < KT) ? (float)(cp - KT + t) : (float)(t - KT);
    }
}

extern "C" void kernel_launch(void* const* d_in, const int* in_sizes, int n_in,
                              void* d_out, int out_size, void* d_ws, size_t ws_size,
                              hipStream_t stream) {
    const float* in_inputs = (const float*)d_in[0];
    const float* in_q = (const float*)d_in[1];
    const float* in_k = (const float*)d_in[2];
    const float* in_v = (const float*)d_in[3];
    const float* in_amask = (const float*)d_in[4];
    const float* in_events = (const float*)d_in[5];
    const void* in_seq = d_in[6];
    float* out = (float*)d_out;

    char* ws = (char*)d_ws;
    double* surprise = (double*)ws;
    float* sims = (float*)(ws + 262144);
    int* bpos = (int*)(ws + 1310720);
    int* nseg = (int*)(ws + 1441792);
    int* idxw = (int*)(ws + 1441824);
    double* qn = (double*)(ws + 1442048);
    float* cval = (float*)(ws + 1442304);
    int* cidx = (int*)(ws + 1444864);
    double* partial = (double*)(ws + 1572864);

    const int fused = (ws_size >= WS_NEED_FUSED) ? 1 : 0;

    bigmove_kernel<<<4096, 256, 0, stream>>>(
        (const float4*)in_inputs, (const float4*)in_q, (const float4*)in_k,
        (const float4*)in_v, (float4*)out, partial, fused);
    if (fused) {
        surprise_reduce_kernel<<<BB * SS / 256, 256, 0, stream>>>(partial,
                                                                  surprise);
    } else {
        surprise_fallback_kernel<<<8192, 256, 0, stream>>>(in_k, surprise);
    }
    stats_scan_kernel<<<4, 1024, 0, stream>>>(surprise, bpos, nseg);
    qnorm_kernel<<<4, 1024, 0, stream>>>(in_k, qn);
    sims_kernel<<<MEM / 4, 256, 0, stream>>>((const float4*)in_events, in_k, qn,
                                             sims);
    topk_part_kernel<<<BB * 16, 256, 0, stream>>>(sims, cval, cidx);
    topk_merge_kernel<<<BB, 256, 0, stream>>>(cval, cidx, idxw);
    gather_kernel<<<BB * KT, 1024, 0, stream>>>(in_events, idxw, out + O2,
                                                out + O3);
    dim3 sg(SS, BB);
    segmean_kernel<<<sg, 256, 0, stream>>>((const float4*)in_k, bpos, nseg,
                                           (float4*)(out + O6), out + O7);
    maskpos_kernel<<<64, 256, 0, stream>>>(in_amask, in_seq, out + O4, out + O5);
}

// Round 3
// 501.908 us; speedup vs baseline: 1.3867x; 1.0472x over previous
//
#include <hip/hip_runtime.h>
#include <math.h>

#define BB 4
#define HH 16
#define SS 8192
#define HDD 64
#define DD 1024
#define MEM 65536
#define KT 10

// ---------------- output offsets (floats) ----------------
static const long O0 = 0;          // inputs      33554432
static const long O1 = 33554432;   // q           33554432
static const long O2 = 67108864;   // aug_k       33595392 (B,H,S+KT,HD)
static const long O3 = 100704256;  // aug_v       33595392
static const long O4 = 134299648;  // aug_mask    32808
static const long O5 = 134332456;  // aug_pos     32808
static const long O6 = 134365264;  // new_events  33554432
static const long O7 = 167919696;  // event_len   32768

// ---------------- ws layout (bytes) ----------------
// 0        double surprise[B*S]        262144   (fallback path only)
// 262144   float  sims[B*MEM]          1048576  -> 1310720
// 1310720  int    bpos[B*S]            131072   -> 1441792
// 1441792  int    nseg[B]
// 1441824  int    idx[B*KT]
// 1442304  float  cval[B*16*10]        2560
// 1444864  int    cidx[B*16*10]        2560     -> 1447424
// 1572864  double partial[B*S*H]       4194304  -> 5767168  (fused path)
#define WS_NEED_FUSED 5767168UL

#define N4REG 8388608L  // float4 per 128MB region

typedef float __attribute__((ext_vector_type(4))) f4v;

static __device__ __forceinline__ void nt_store4(float4* p, float4 v) {
    f4v t; t.x = v.x; t.y = v.y; t.z = v.z; t.w = v.w;
    __builtin_nontemporal_store(t, (f4v*)p);
}
static __device__ __forceinline__ float4 nt_load4(const float4* p) {
    f4v t = __builtin_nontemporal_load((const f4v*)p);
    float4 v; v.x = t.x; v.y = t.y; v.z = t.z; v.w = t.w;
    return v;
}

// ------------------------------------------------------------------
// Band 0..3 (4096 blocks): copy inputs/q/k/v (k also emits surprise partials,
//   transposed layout partial[b][s][h]).
// Band 4 (16384 blocks): sims (f32, no qn — positive per-batch scale cannot
//   change per-batch ranking; top-10 spacing ~3.6e-3 >> f32 error ~1e-5).
// Band 5 (2048 blocks): pre-zero new_events + event_lengths (streamed).
#define R0_BLOCKS 4096
#define R1_BLOCKS 16384
#define R2_BLOCKS 2048
__global__ __launch_bounds__(256) void bigfused_kernel(
        const float4* __restrict__ in0, const float4* __restrict__ q,
        const float4* __restrict__ k4, const float* __restrict__ kf,
        const float4* __restrict__ v, const float4* __restrict__ events4,
        float4* __restrict__ out4, double* __restrict__ partial,
        float* __restrict__ sims, int do_part) {
    __shared__ float4 qls4[BB][256];
    int blk = blockIdx.x;
    int tid = threadIdx.x;
    if (blk < R0_BLOCKS) {
        int band = blk >> 10;
        long i = ((long)(blk & 1023)) * 256 + tid;
        const long bstride = 1024L * 256;
        if (band == 0) {
            for (; i < N4REG; i += bstride)
                nt_store4(out4 + (O0 >> 2) + i, nt_load4(in0 + i));
        } else if (band == 1) {
            for (; i < N4REG; i += bstride)
                nt_store4(out4 + (O1 >> 2) + i, nt_load4(q + i));
        } else if (band == 3) {
            for (; i < N4REG; i += bstride) {
                long chunk = i >> 17;  // (b*H+h), 131072 float4 per slice
                long r = i & 131071;
                nt_store4(out4 + (O3 >> 2) + chunk * 131232 + 160 + r,
                          nt_load4(v + i));
            }
        } else {  // band 2: k interior copy + surprise partials
            for (; i < N4REG; i += bstride) {
                long chunk = i >> 17;
                long r = i & 131071;
                float4 cur = k4[i];  // cached: k re-read by segmean later
                nt_store4(out4 + (O2 >> 2) + chunk * 131232 + 160 + r, cur);
                if (do_part) {
                    int s = (int)(r >> 4);  // 16 float4 per row
                    if (s > 0) {
                        float4 pv = k4[i - 16];
                        double dx = (double)cur.x - (double)pv.x;
                        double dy = (double)cur.y - (double)pv.y;
                        double dz = (double)cur.z - (double)pv.z;
                        double dw = (double)cur.w - (double)pv.w;
                        double acc = dx * dx + dy * dy + dz * dz + dw * dw;
                        acc += __shfl_xor(acc, 1, 64);
                        acc += __shfl_xor(acc, 2, 64);
                        acc += __shfl_xor(acc, 4, 64);
                        acc += __shfl_xor(acc, 8, 64);
                        if ((tid & 15) == 0) {
                            int b = (int)(chunk >> 4);
                            int h = (int)(chunk & 15);
                            partial[((long)b * SS + s) * HH + h] = acc;
                        }
                    }
                }
            }
        }
    } else if (blk < R0_BLOCKS + R1_BLOCKS) {
        // sims: one event row per wave, 4 batches per row
        for (int j = tid; j < BB * 256; j += 256) {
            int b = j >> 8;
            int f4i = j & 255;  // h = f4i>>4, within-row f4 = f4i&15
            qls4[b][f4i] =
                k4[((long)(b * HH + (f4i >> 4)) * SS + (SS - 1)) * 16 + (f4i & 15)];
        }
        __syncthreads();
        int w = tid >> 6;
        int lane = tid & 63;
        long e = (long)(blk - R0_BLOCKS) * 4 + w;
        const float4* er = events4 + e * 256;
        float en = 0.f, d0 = 0.f, d1 = 0.f, d2 = 0.f, d3 = 0.f;
#pragma unroll
        for (int it = 0; it < 4; ++it) {
            int j4 = lane + it * 64;
            float4 ev = nt_load4(er + j4);
            en += ev.x * ev.x + ev.y * ev.y + ev.z * ev.z + ev.w * ev.w;
            float4 q0 = qls4[0][j4];
            d0 += ev.x * q0.x + ev.y * q0.y + ev.z * q0.z + ev.w * q0.w;
            float4 q1 = qls4[1][j4];
            d1 += ev.x * q1.x + ev.y * q1.y + ev.z * q1.z + ev.w * q1.w;
            float4 q2 = qls4[2][j4];
            d2 += ev.x * q2.x + ev.y * q2.y + ev.z * q2.z + ev.w * q2.w;
            float4 q3 = qls4[3][j4];
            d3 += ev.x * q3.x + ev.y * q3.y + ev.z * q3.z + ev.w * q3.w;
        }
        for (int m = 32; m >= 1; m >>= 1) {
            en += __shfl_xor(en, m, 64);
            d0 += __shfl_xor(d0, m, 64);
            d1 += __shfl_xor(d1, m, 64);
            d2 += __shfl_xor(d2, m, 64);
            d3 += __shfl_xor(d3, m, 64);
        }
        if (lane == 0) {
            float enn = fmaxf(sqrtf(en), 1e-8f);
            sims[0 * (long)MEM + e] = d0 / enn;
            sims[1 * (long)MEM + e] = d1 / enn;
            sims[2 * (long)MEM + e] = d2 / enn;
            sims[3 * (long)MEM + e] = d3 / enn;
        }
    } else {
        // pre-zero new_events (8388608 f4) + event_lengths (8192 f4)
        long i = ((long)(blk - R0_BLOCKS - R1_BLOCKS)) * 256 + tid;
        const long stride = (long)R2_BLOCKS * 256;
        const float4 z = make_float4(0.f, 0.f, 0.f, 0.f);
        for (; i < 8396800L; i += stride) {
            if (i < 8388608L)
                nt_store4(out4 + (O6 >> 2) + i, z);
            else
                nt_store4(out4 + (O7 >> 2) + (i - 8388608L), z);
        }
    }
}

// fallback (small ws): standalone surprise pass reading k directly
__global__ __launch_bounds__(256) void surprise_fallback_kernel(
        const float* __restrict__ k, double* __restrict__ surprise) {
    int wid = (int)(((long)blockIdx.x * blockDim.x + threadIdx.x) >> 6);
    int lane = threadIdx.x & 63;
    if (wid >= BB * SS) return;
    int b = wid >> 13;
    int s = wid & (SS - 1);
    double acc = 0.0;
    if (s > 0) {
        const float* kb = k + (long)b * HH * SS * HDD;
        for (int h = 0; h < HH; ++h) {
            long off = ((long)h * SS + s) * HDD + lane;
            double d = (double)kb[off] - (double)kb[off - HDD];
            acc += d * d;
        }
        for (int m = 32; m >= 1; m >>= 1) acc += __shfl_xor(acc, m, 64);
    }
    if (lane == 0) surprise[wid] = (s == 0) ? 0.0 : sqrt(acc);
}

// per-batch: surprise (from partials) -> mean/std(ddof=1) -> boundaries -> bpos
__global__ __launch_bounds__(1024) void stats_scan_kernel(
        const double* __restrict__ partial, const double* __restrict__ surprise,
        int* __restrict__ bpos, int* __restrict__ nseg, int fused) {
    int b = blockIdx.x;
    int tid = threadIdx.x;
    double loc[8];
    double sum = 0.0;
    if (fused) {
        const double* pb = partial + (long)b * SS * HH;
        for (int j = 0; j < 8; ++j) {
            int s = tid * 8 + j;
            double acc = 0.0;
            if (s > 0) {
                const double* row = pb + (long)s * HH;
                for (int h = 0; h < HH; ++h) acc += row[h];
            }
            loc[j] = (s == 0) ? 0.0 : sqrt(acc);
            sum += loc[j];
        }
    } else {
        const double* sp = surprise + (long)b * SS;
        for (int j = 0; j < 8; ++j) { loc[j] = sp[tid * 8 + j]; sum += loc[j]; }
    }
    __shared__ double sd[1024];
    sd[tid] = sum;
    __syncthreads();
    for (int off = 512; off >= 1; off >>= 1) {
        if (tid < off) sd[tid] += sd[tid + off];
        __syncthreads();
    }
    double mean = sd[0] / SS;
    __syncthreads();
    double vs = 0.0;
    for (int j = 0; j < 8; ++j) { double d = loc[j] - mean; vs += d * d; }
    sd[tid] = vs;
    __syncthreads();
    for (int off = 512; off >= 1; off >>= 1) {
        if (tid < off) sd[tid] += sd[tid + off];
        __syncthreads();
    }
    double thr = mean + 0.5 * sqrt(sd[0] / (SS - 1));
    __syncthreads();

    int bi[8];
    int cnt = 0;
    for (int j = 0; j < 8; ++j) {
        int s = tid * 8 + j;
        bi[j] = (s == SS - 1) || (loc[j] > thr);
        cnt += bi[j];
    }
    __shared__ int si[1024];
    si[tid] = cnt;
    __syncthreads();
    for (int off = 1; off < 1024; off <<= 1) {
        int v = 0;
        if (tid >= off) v = si[tid - off];
        __syncthreads();
        si[tid] += v;
        __syncthreads();
    }
    int run = si[tid] - cnt;  // exclusive prefix
    for (int j = 0; j < 8; ++j) {
        if (bi[j]) { bpos[(long)b * SS + run] = tid * 8 + j; ++run; }
    }
    if (tid == 1023) nseg[b] = si[1023];
}

// stage 1: per (batch, partition of 4096) exact top-10, ties -> lowest index
__global__ __launch_bounds__(256) void topk_part_kernel(
        const float* __restrict__ sims, float* __restrict__ cval,
        int* __restrict__ cidx) {
    int blk = blockIdx.x;  // b*16 + part
    int b = blk >> 4;
    int part = blk & 15;
    const float* sb = sims + (long)b * MEM + part * 4096;
    int base = part * 4096;
    int tid = threadIdx.x;
    __shared__ float bv[256];
    __shared__ int bix[256];
    __shared__ int chosen[KT];
    for (int p = 0; p < KT; ++p) {
        float best = -INFINITY;
        int bi = 0x7fffffff;
        for (int it = 0; it < 16; ++it) {
            int e = tid + it * 256;  // increasing per thread
            bool skip = false;
            for (int c = 0; c < p; ++c)
                if (chosen[c] == e) skip = true;
            if (skip) continue;
            float v = sb[e];
            if (v > best) { best = v; bi = e; }
        }
        bv[tid] = best;
        bix[tid] = bi;
        __syncthreads();
        for (int off = 128; off >= 1; off >>= 1) {
            if (tid < off) {
                if (bv[tid + off] > bv[tid] ||
                    (bv[tid + off] == bv[tid] && bix[tid + off] < bix[tid])) {
                    bv[tid] = bv[tid + off];
                    bix[tid] = bix[tid + off];
                }
            }
            __syncthreads();
        }
        if (tid == 0) {
            chosen[p] = bix[0];
            cval[blk * KT + p] = bv[0];
            cidx[blk * KT + p] = base + bix[0];
        }
        __syncthreads();
    }
}

// stage 2: merge 16*10 candidates per batch -> global top-10
__global__ __launch_bounds__(256) void topk_merge_kernel(
        const float* __restrict__ cval, const int* __restrict__ cidx,
        int* __restrict__ idxout) {
    int b = blockIdx.x;
    int tid = threadIdx.x;
    __shared__ float v[256];
    __shared__ int ix[256];
    float mv = -INFINITY;
    int mi = 0x7fffffff;
    if (tid < 160) { mv = cval[b * 160 + tid]; mi = cidx[b * 160 + tid]; }
    v[tid] = mv;
    ix[tid] = mi;
    __syncthreads();
    if (tid == 0) {
        for (int p = 0; p < KT; ++p) {
            float best = -INFINITY;
            int bi = 0x7fffffff;
            int bslot = 0;
            for (int j = 0; j < 160; ++j) {
                if (v[j] > best || (v[j] == best && ix[j] < bi)) {
                    best = v[j];
                    bi = ix[j];
                    bslot = j;
                }
            }
            idxout[b * KT + p] = bi;
            v[bslot] = -INFINITY;
            ix[bslot] = 0x7fffffff;
        }
    }
}

// gather top-k rows into aug fronts (blocks 0..39) + mask/positions (40..103)
__global__ __launch_bounds__(256) void tail_kernel(
        const float* __restrict__ events, const int* __restrict__ idxin,
        const float* __restrict__ amask, const void* __restrict__ seqp,
        float* __restrict__ out) {
    int blk = blockIdx.x;
    int tid = threadIdx.x;
    if (blk < BB * KT) {
        int b = blk / KT;
        int t = blk % KT;
        int ev = idxin[b * KT + t];
        for (int c = 0; c < 4; ++c) {
            int j = tid + c * 256;
            float vv = events[(long)ev * DD + j];
            int h = j >> 6;
            int d = j & 63;
            long dst = (((long)b * HH + h) * (SS + KT) + t) * HDD + d;
            out[O2 + dst] = vv;
            out[O3 + dst] = vv;
        }
    } else {
        int iv = ((const int*)seqp)[0];
        int seqlen;
        if (iv > 0 && iv < (1 << 24)) seqlen = iv;
        else seqlen = (int)(((const float*)seqp)[0]);
        int cp = seqlen - 1;
        int n = BB * (SS + KT);
        int i = (blk - BB * KT) * 256 + tid;
        int stride = 64 * 256;
        for (; i < n; i += stride) {
            int b = i / (SS + KT);
            int t = i - b * (SS + KT);
            out[O4 + i] = (t < KT) ? 1.0f : amask[(long)b * SS + t - KT];
            out[O5 + i] = (t < KT) ? (float)(cp - KT + t) : (float)(t - KT);
        }
    }
}

// segment means -> new_events (active rows only; zeros pre-written)
__global__ __launch_bounds__(256) void segmean_kernel(
        const float4* __restrict__ k4, const int* __restrict__ bpos,
        const int* __restrict__ nseg, float4* __restrict__ ne4,
        float* __restrict__ event_lengths) {
    int j = blockIdx.x;  // segment slot in [0,S)
    int b = blockIdx.y;
    int ns = nseg[b];
    if (j >= ns) return;
    int tid = threadIdx.x;
    float4* row = ne4 + ((long)b * SS + j) * 256;
    int start = (j == 0) ? 0 : bpos[(long)b * SS + j - 1] + 1;
    int end = bpos[(long)b * SS + j];
    const float4* kb = k4 + ((long)(b * HH + (tid >> 4)) * SS) * 16 + (tid & 15);
    double a0 = 0.0, a1 = 0.0, a2 = 0.0, a3 = 0.0;
    for (int s = start; s <= end; ++s) {
        float4 x = kb[(long)s * 16];
        a0 += (double)x.x;
        a1 += (double)x.y;
        a2 += (double)x.z;
        a3 += (double)x.w;
    }
    double inv = 1.0 / (double)(end - start + 1);
    nt_store4(row + tid, make_float4((float)(a0 * inv), (float)(a1 * inv),
                                     (float)(a2 * inv), (float)(a3 * inv)));
    if (tid == 0) event_lengths[(long)b * SS + j] = (float)(end - start + 1);
}

extern "C" void kernel_launch(void* const* d_in, const int* in_sizes, int n_in,
                              void* d_out, int out_size, void* d_ws, size_t ws_size,
                              hipStream_t stream) {
    const float* in_inputs = (const float*)d_in[0];
    const float* in_q = (const float*)d_in[1];
    const float* in_k = (const float*)d_in[2];
    const float* in_v = (const float*)d_in[3];
    const float* in_amask = (const float*)d_in[4];
    const float* in_events = (const float*)d_in[5];
    const void* in_seq = d_in[6];
    float* out = (float*)d_out;

    char* ws = (char*)d_ws;
    double* surprise = (double*)ws;
    float* sims = (float*)(ws + 262144);
    int* bpos = (int*)(ws + 1310720);
    int* nseg = (int*)(ws + 1441792);
    int* idxw = (int*)(ws + 1441824);
    float* cval = (float*)(ws + 1442304);
    int* cidx = (int*)(ws + 1444864);
    double* partial = (double*)(ws + 1572864);

    const int fused = (ws_size >= WS_NEED_FUSED) ? 1 : 0;

    bigfused_kernel<<<R0_BLOCKS + R1_BLOCKS + R2_BLOCKS, 256, 0, stream>>>(
        (const float4*)in_inputs, (const float4*)in_q, (const float4*)in_k,
        in_k, (const float4*)in_v, (const float4*)in_events, (float4*)out,
        partial, sims, fused);
    if (!fused)
        surprise_fallback_kernel<<<8192, 256, 0, stream>>>(in_k, surprise);
    stats_scan_kernel<<<4, 1024, 0, stream>>>(partial, surprise, bpos, nseg,
                                              fused);
    topk_part_kernel<<<BB * 16, 256, 0, stream>>>(sims, cval, cidx);
    topk_merge_kernel<<<BB, 256, 0, stream>>>(cval, cidx, idxw);
    tail_kernel<<<BB * KT + 64, 256, 0, stream>>>(in_events, idxw, in_amask,
                                                  in_seq, out);
    dim3 sg(SS, BB);
    segmean_kernel<<<sg, 256, 0, stream>>>((const float4*)in_k, bpos, nseg,
                                           (float4*)(out + O6), out + O7);
}

// Round 4
// 433.506 us; speedup vs baseline: 1.6055x; 1.1578x over previous
//
#include <hip/hip_runtime.h>
#include <math.h>

#define BB 4
#define HH 16
#define SS 8192
#define HDD 64
#define DD 1024
#define MEM 65536
#define KT 10
#define AUGROWS (SS + KT)

// ---------------- output offsets (floats) ----------------
static const long O0 = 0;          // inputs      33554432
static const long O1 = 33554432;   // q           33554432
static const long O2 = 67108864;   // aug_k       33595392 (B,H,S+KT,HD)
static const long O3 = 100704256;  // aug_v       33595392
static const long O4 = 134299648;  // aug_mask    32808
static const long O5 = 134332456;  // aug_pos     32808
static const long O6 = 134365264;  // new_events  33554432
static const long O7 = 167919696;  // event_len   32768

// ---------------- ws layout (bytes) ----------------
// 0        double surprise[B*S]        262144
// 262144   float  sims[B*MEM]          1048576  -> 1310720
// 1310720  int    bpos[B*S]            131072   -> 1441792
// 1441792  int    nseg[B]
// 1441824  int    idx[B*KT]
// 1442304  float  cval[B*16*10]        2560
// 1444864  int    cidx[B*16*10]        2560     -> 1447424
// 1572864  double partial[B*S*H]       4194304  -> 5767168  (fused path)
#define WS_NEED_FUSED 5767168UL

#define N4REG 8388608L  // float4 per 128MB region

typedef float __attribute__((ext_vector_type(4))) f4v;

static __device__ __forceinline__ void nt_store4(float4* p, float4 v) {
    f4v t; t.x = v.x; t.y = v.y; t.z = v.z; t.w = v.w;
    __builtin_nontemporal_store(t, (f4v*)p);
}
static __device__ __forceinline__ float4 nt_load4(const float4* p) {
    f4v t = __builtin_nontemporal_load((const f4v*)p);
    float4 v; v.x = t.x; v.y = t.y; v.z = t.z; v.w = t.w;
    return v;
}

// ------------------------------------------------------------------
// Bands: 0 inputs, 1 q, 2 k(+partials, PLAIN stores -> L3-resident aug_k),
//        3 v, 4 sims. Stream-once data uses NT loads/stores.
#define COPY_BLOCKS 4096
#define SIMS_BLOCKS 4096
__global__ __launch_bounds__(256) void bigfused_kernel(
        const float4* __restrict__ in0, const float4* __restrict__ q,
        const float4* __restrict__ k4, const float4* __restrict__ v,
        const float4* __restrict__ events4, float4* __restrict__ out4,
        double* __restrict__ partial, float* __restrict__ sims, int do_part) {
    __shared__ float4 qls4[BB][256];
    int blk = blockIdx.x;
    int tid = threadIdx.x;
    if (blk < COPY_BLOCKS) {
        int band = blk >> 10;
        long i = ((long)(blk & 1023)) * 256 + tid;
        const long bstride = 1024L * 256;
        if (band == 0) {
            for (; i < N4REG; i += bstride)
                nt_store4(out4 + (O0 >> 2) + i, nt_load4(in0 + i));
        } else if (band == 1) {
            for (; i < N4REG; i += bstride)
                nt_store4(out4 + (O1 >> 2) + i, nt_load4(q + i));
        } else if (band == 3) {
            for (; i < N4REG; i += bstride) {
                long chunk = i >> 17;  // (b*H+h), 131072 float4 per slice
                long r = i & 131071;
                nt_store4(out4 + (O3 >> 2) + chunk * 131232L + 160 + r,
                          nt_load4(v + i));
            }
        } else {  // band 2: k interior copy (plain) + surprise partials
            for (; i < N4REG; i += bstride) {
                long chunk = i >> 17;
                long r = i & 131071;
                float4 cur = k4[i];
                out4[(O2 >> 2) + chunk * 131232L + 160 + r] = cur;
                if (do_part) {
                    int s = (int)(r >> 4);  // 16 float4 per row
                    if (s > 0) {
                        float4 pv = k4[i - 16];
                        double dx = (double)cur.x - (double)pv.x;
                        double dy = (double)cur.y - (double)pv.y;
                        double dz = (double)cur.z - (double)pv.z;
                        double dw = (double)cur.w - (double)pv.w;
                        double acc = dx * dx + dy * dy + dz * dz + dw * dw;
                        acc += __shfl_xor(acc, 1, 64);
                        acc += __shfl_xor(acc, 2, 64);
                        acc += __shfl_xor(acc, 4, 64);
                        acc += __shfl_xor(acc, 8, 64);
                        if ((tid & 15) == 0) {
                            int b = (int)(chunk >> 4);
                            int h = (int)(chunk & 15);
                            partial[((long)b * SS + s) * HH + h] = acc;
                        }
                    }
                }
            }
        }
    } else {
        // sims: 4 rows per wave (stride 4*SIMS_BLOCKS), stage query once
        for (int j = tid; j < BB * 256; j += 256) {
            int b = j >> 8;
            int f4i = j & 255;
            qls4[b][f4i] =
                k4[((long)(b * HH + (f4i >> 4)) * SS + (SS - 1)) * 16 + (f4i & 15)];
        }
        __syncthreads();
        int w = tid >> 6;
        int lane = tid & 63;
        long e0 = (long)(blk - COPY_BLOCKS) * 4 + w;
        for (int rr = 0; rr < 4; ++rr) {
            long e = e0 + (long)rr * (4 * SIMS_BLOCKS);
            const float4* er = events4 + e * 256;
            float en = 0.f, d0 = 0.f, d1 = 0.f, d2 = 0.f, d3 = 0.f;
#pragma unroll
            for (int it = 0; it < 4; ++it) {
                int j4 = lane + it * 64;
                float4 ev = nt_load4(er + j4);
                en += ev.x * ev.x + ev.y * ev.y + ev.z * ev.z + ev.w * ev.w;
                float4 q0 = qls4[0][j4];
                d0 += ev.x * q0.x + ev.y * q0.y + ev.z * q0.z + ev.w * q0.w;
                float4 q1 = qls4[1][j4];
                d1 += ev.x * q1.x + ev.y * q1.y + ev.z * q1.z + ev.w * q1.w;
                float4 q2 = qls4[2][j4];
                d2 += ev.x * q2.x + ev.y * q2.y + ev.z * q2.z + ev.w * q2.w;
                float4 q3 = qls4[3][j4];
                d3 += ev.x * q3.x + ev.y * q3.y + ev.z * q3.z + ev.w * q3.w;
            }
            for (int m = 32; m >= 1; m >>= 1) {
                en += __shfl_xor(en, m, 64);
                d0 += __shfl_xor(d0, m, 64);
                d1 += __shfl_xor(d1, m, 64);
                d2 += __shfl_xor(d2, m, 64);
                d3 += __shfl_xor(d3, m, 64);
            }
            if (lane == 0) {
                float enn = fmaxf(sqrtf(en), 1e-8f);
                sims[0 * (long)MEM + e] = d0 / enn;
                sims[1 * (long)MEM + e] = d1 / enn;
                sims[2 * (long)MEM + e] = d2 / enn;
                sims[3 * (long)MEM + e] = d3 / enn;
            }
        }
    }
}

// parallel h-reduction of partials -> surprise[b*S+s]
__global__ __launch_bounds__(1024) void surprise_reduce_kernel(
        const double* __restrict__ partial, double* __restrict__ surprise) {
    int t = blockIdx.x * 1024 + threadIdx.x;
    if (t >= BB * SS) return;
    int s = t & (SS - 1);
    double acc = 0.0;
    if (s > 0) {
        const double* row = partial + (long)t * HH;
#pragma unroll
        for (int h = 0; h < HH; ++h) acc += row[h];
    }
    surprise[t] = (s == 0) ? 0.0 : sqrt(acc);
}

// fallback (small ws): standalone surprise pass reading k directly
__global__ __launch_bounds__(256) void surprise_fallback_kernel(
        const float* __restrict__ k, double* __restrict__ surprise) {
    int wid = (int)(((long)blockIdx.x * blockDim.x + threadIdx.x) >> 6);
    int lane = threadIdx.x & 63;
    if (wid >= BB * SS) return;
    int b = wid >> 13;
    int s = wid & (SS - 1);
    double acc = 0.0;
    if (s > 0) {
        const float* kb = k + (long)b * HH * SS * HDD;
        for (int h = 0; h < HH; ++h) {
            long off = ((long)h * SS + s) * HDD + lane;
            double d = (double)kb[off] - (double)kb[off - HDD];
            acc += d * d;
        }
        for (int m = 32; m >= 1; m >>= 1) acc += __shfl_xor(acc, m, 64);
    }
    if (lane == 0) surprise[wid] = (s == 0) ? 0.0 : sqrt(acc);
}

// per-batch: mean/std(ddof=1) -> threshold -> boundary mask -> scan -> bpos
__global__ __launch_bounds__(1024) void stats_scan_kernel(
        const double* __restrict__ surprise, int* __restrict__ bpos,
        int* __restrict__ nseg) {
    int b = blockIdx.x;
    int tid = threadIdx.x;
    const double* sp = surprise + (long)b * SS;
    double loc[8];
    double sum = 0.0;
    for (int j = 0; j < 8; ++j) { loc[j] = sp[tid * 8 + j]; sum += loc[j]; }
    __shared__ double sd[1024];
    sd[tid] = sum;
    __syncthreads();
    for (int off = 512; off >= 1; off >>= 1) {
        if (tid < off) sd[tid] += sd[tid + off];
        __syncthreads();
    }
    double mean = sd[0] / SS;
    __syncthreads();
    double vs = 0.0;
    for (int j = 0; j < 8; ++j) { double d = loc[j] - mean; vs += d * d; }
    sd[tid] = vs;
    __syncthreads();
    for (int off = 512; off >= 1; off >>= 1) {
        if (tid < off) sd[tid] += sd[tid + off];
        __syncthreads();
    }
    double thr = mean + 0.5 * sqrt(sd[0] / (SS - 1));
    __syncthreads();

    int bi[8];
    int cnt = 0;
    for (int j = 0; j < 8; ++j) {
        int s = tid * 8 + j;
        bi[j] = (s == SS - 1) || (loc[j] > thr);
        cnt += bi[j];
    }
    __shared__ int si[1024];
    si[tid] = cnt;
    __syncthreads();
    for (int off = 1; off < 1024; off <<= 1) {
        int v = 0;
        if (tid >= off) v = si[tid - off];
        __syncthreads();
        si[tid] += v;
        __syncthreads();
    }
    int run = si[tid] - cnt;  // exclusive prefix
    for (int j = 0; j < 8; ++j) {
        if (bi[j]) { bpos[(long)b * SS + run] = tid * 8 + j; ++run; }
    }
    if (tid == 1023) nseg[b] = si[1023];
}

// single-pass top-10: per-thread register insertion + LDS list-merge
__global__ __launch_bounds__(256) void topk_part_kernel(
        const float* __restrict__ sims, float* __restrict__ cval,
        int* __restrict__ cidx) {
    int blk = blockIdx.x;  // b*16 + part
    int b = blk >> 4;
    int part = blk & 15;
    const float* sb = sims + (long)b * MEM + part * 4096;
    int base = part * 4096;
    int tid = threadIdx.x;

    float val[KT];
    int idx[KT];
#pragma unroll
    for (int p = 0; p < KT; ++p) { val[p] = -INFINITY; idx[p] = 0x7fffffff; }
    // scan 16 values in increasing-index order
    for (int it = 0; it < 16; ++it) {
        int e = tid + it * 256;
        float v = sb[e];
        if (v > val[KT - 1]) {  // ties with current 10th lose (higher idx)
#pragma unroll
            for (int p = KT - 1; p >= 1; --p) {
                if (v > val[p - 1]) {
                    val[p] = val[p - 1];
                    idx[p] = idx[p - 1];
                } else {
                    val[p] = v;
                    idx[p] = e;
                    v = -INFINITY;  // placed; stop shifting
                }
            }
            if (v != -INFINITY) { val[0] = v; idx[0] = e; }
        }
    }
    __shared__ float lv[256][KT];
    __shared__ int li[256][KT];
#pragma unroll
    for (int p = 0; p < KT; ++p) { lv[tid][p] = val[p]; li[tid][p] = idx[p]; }
    for (int off = 128; off >= 1; off >>= 1) {
        __syncthreads();
        if (tid < off) {
            float a_[KT], b_[KT], m_[KT];
            int ai_[KT], bi_[KT], mi_[KT];
#pragma unroll
            for (int p = 0; p < KT; ++p) {
                a_[p] = lv[tid][p];
                ai_[p] = li[tid][p];
                b_[p] = lv[tid + off][p];
                bi_[p] = li[tid + off][p];
            }
            int pa = 0, pb = 0;
#pragma unroll
            for (int p = 0; p < KT; ++p) {
                bool ta = (a_[pa] > b_[pb]) ||
                          (a_[pa] == b_[pb] && ai_[pa] < bi_[pb]);
                if (ta) { m_[p] = a_[pa]; mi_[p] = ai_[pa]; ++pa; }
                else    { m_[p] = b_[pb]; mi_[p] = bi_[pb]; ++pb; }
            }
#pragma unroll
            for (int p = 0; p < KT; ++p) { lv[tid][p] = m_[p]; li[tid][p] = mi_[p]; }
        }
    }
    __syncthreads();
    if (tid == 0) {
#pragma unroll
        for (int p = 0; p < KT; ++p) {
            cval[blk * KT + p] = lv[0][p];
            cidx[blk * KT + p] = base + li[0][p];
        }
    }
}

// merge 16*10 candidates per batch -> global top-10
__global__ __launch_bounds__(256) void topk_merge_kernel(
        const float* __restrict__ cval, const int* __restrict__ cidx,
        int* __restrict__ idxout) {
    int b = blockIdx.x;
    int tid = threadIdx.x;
    __shared__ float v[256];
    __shared__ int ix[256];
    float mv = -INFINITY;
    int mi = 0x7fffffff;
    if (tid < 160) { mv = cval[b * 160 + tid]; mi = cidx[b * 160 + tid]; }
    v[tid] = mv;
    ix[tid] = mi;
    __syncthreads();
    if (tid == 0) {
        for (int p = 0; p < KT; ++p) {
            float best = -INFINITY;
            int bi = 0x7fffffff;
            int bslot = 0;
            for (int j = 0; j < 160; ++j) {
                if (v[j] > best || (v[j] == best && ix[j] < bi)) {
                    best = v[j];
                    bi = ix[j];
                    bslot = j;
                }
            }
            idxout[b * KT + p] = bi;
            v[bslot] = -INFINITY;
            ix[bslot] = 0x7fffffff;
        }
    }
}

// segment means (reads aug_k, ~L3-hot) + zero rows + gather fronts + mask/pos
__global__ __launch_bounds__(256) void segtail_kernel(
        const float4* __restrict__ out4c, const int* __restrict__ bpos,
        const int* __restrict__ nseg, const float* __restrict__ events,
        const int* __restrict__ idxin, const float* __restrict__ amask,
        const void* __restrict__ seqp, float* __restrict__ out) {
    int blk = blockIdx.x;
    int tid = threadIdx.x;
    float4* ne4 = (float4*)(out + O6);
    if (blk < BB * SS) {
        int b = blk >> 13;
        int j = blk & (SS - 1);
        int ns = nseg[b];
        float4* row = ne4 + ((long)b * SS + j) * 256;
        if (j >= ns) {
            nt_store4(row + tid, make_float4(0.f, 0.f, 0.f, 0.f));
            if (tid == 0) out[O7 + (long)b * SS + j] = 0.0f;
            return;
        }
        int start = (j == 0) ? 0 : bpos[(long)b * SS + j - 1] + 1;
        int end = bpos[(long)b * SS + j];
        const float4* kb = out4c + (O2 >> 2) +
                           ((long)(b * HH + (tid >> 4)) * AUGROWS + KT) * 16 +
                           (tid & 15);
        double a0 = 0.0, a1 = 0.0, a2 = 0.0, a3 = 0.0;
        for (int s = start; s <= end; ++s) {
            float4 x = kb[(long)s * 16];
            a0 += (double)x.x;
            a1 += (double)x.y;
            a2 += (double)x.z;
            a3 += (double)x.w;
        }
        double inv = 1.0 / (double)(end - start + 1);
        nt_store4(row + tid, make_float4((float)(a0 * inv), (float)(a1 * inv),
                                         (float)(a2 * inv), (float)(a3 * inv)));
        if (tid == 0) out[O7 + (long)b * SS + j] = (float)(end - start + 1);
    } else if (blk < BB * SS + BB * KT) {
        int g = blk - BB * SS;
        int b = g / KT;
        int t = g % KT;
        int ev = idxin[b * KT + t];
        for (int c = 0; c < 4; ++c) {
            int j = tid + c * 256;
            float vv = events[(long)ev * DD + j];
            int h = j >> 6;
            int d = j & 63;
            long dst = (((long)b * HH + h) * AUGROWS + t) * HDD + d;
            out[O2 + dst] = vv;
            out[O3 + dst] = vv;
        }
    } else {
        int iv = ((const int*)seqp)[0];
        int seqlen;
        if (iv > 0 && iv < (1 << 24)) seqlen = iv;
        else seqlen = (int)(((const float*)seqp)[0]);
        int cp = seqlen - 1;
        int n = BB * AUGROWS;
        int i = (blk - BB * SS - BB * KT) * 256 + tid;
        int stride = 64 * 256;
        for (; i < n; i += stride) {
            int b = i / AUGROWS;
            int t = i - b * AUGROWS;
            out[O4 + i] = (t < KT) ? 1.0f : amask[(long)b * SS + t - KT];
            out[O5 + i] = (t < KT) ? (float)(cp - KT + t) : (float)(t - KT);
        }
    }
}

extern "C" void kernel_launch(void* const* d_in, const int* in_sizes, int n_in,
                              void* d_out, int out_size, void* d_ws, size_t ws_size,
                              hipStream_t stream) {
    const float* in_inputs = (const float*)d_in[0];
    const float* in_q = (const float*)d_in[1];
    const float* in_k = (const float*)d_in[2];
    const float* in_v = (const float*)d_in[3];
    const float* in_amask = (const float*)d_in[4];
    const float* in_events = (const float*)d_in[5];
    const void* in_seq = d_in[6];
    float* out = (float*)d_out;

    char* ws = (char*)d_ws;
    double* surprise = (double*)ws;
    float* sims = (float*)(ws + 262144);
    int* bpos = (int*)(ws + 1310720);
    int* nseg = (int*)(ws + 1441792);
    int* idxw = (int*)(ws + 1441824);
    float* cval = (float*)(ws + 1442304);
    int* cidx = (int*)(ws + 1444864);
    double* partial = (double*)(ws + 1572864);

    const int fused = (ws_size >= WS_NEED_FUSED) ? 1 : 0;

    bigfused_kernel<<<COPY_BLOCKS + SIMS_BLOCKS, 256, 0, stream>>>(
        (const float4*)in_inputs, (const float4*)in_q, (const float4*)in_k,
        (const float4*)in_v, (const float4*)in_events, (float4*)out, partial,
        sims, fused);
    if (fused) {
        surprise_reduce_kernel<<<32, 1024, 0, stream>>>(partial, surprise);
    } else {
        surprise_fallback_kernel<<<8192, 256, 0, stream>>>(in_k, surprise);
    }
    stats_scan_kernel<<<4, 1024, 0, stream>>>(surprise, bpos, nseg);
    topk_part_kernel<<<BB * 16, 256, 0, stream>>>(sims, cval, cidx);
    topk_merge_kernel<<<BB, 256, 0, stream>>>(cval, cidx, idxw);
    segtail_kernel<<<BB * SS + BB * KT + 64, 256, 0, stream>>>(
        (const float4*)out, bpos, nseg, in_events, idxw, in_amask, in_seq, out);
}